// Round 8
// baseline (386.241 us; speedup 1.0000x reference)
//
#include <hip/hip_runtime.h>
#include <hip/hip_bf16.h>

typedef __hip_bfloat16 bf16;
typedef unsigned int uint;
typedef unsigned short ushort;

using frag  = __attribute__((ext_vector_type(8))) short;
using f32x4 = __attribute__((ext_vector_type(4))) float;

// ---- static device scratch (immune to ws_size; fully rewritten every call) ----
__device__ bf16  g_volT[8ULL*262144*16]; // feat channel-last bf16 [b][z][y][x][16]
__device__ bf16  g_imgT[8*4096*16];      // render out channel-last [b][64][64][16]
__device__ bf16  g_t1 [8*16384*16];      // convT raw channel-last [b][128][128][16]
__device__ bf16  g_a2r[8*16384*8];       // conv1 raw channel-last [b][128][128][8]
__device__ float g_sil[8*4096];
__device__ float g_part [512*32];        // convT BN1 partials (16 sum + 16 sq)
__device__ float g_part2[256*16];        // conv1 BN2 partials (8 sum + 8 sq)
__device__ float g_stats[96];            // [32:48]a1 [48:64]b1 [80:88]a2 [88:96]b2
__device__ bf16  g_wAt[4*5*64*8];        // packed A-frags: convT (class,step,lane,j)
__device__ bf16  g_wA1[13*64*8];         // conv1
__device__ bf16  g_wA2[7*64*8];          // conv2
__device__ uint  g_ctr1, g_ctr2;         // last-block counters (reset each call)

__device__ __forceinline__ float bup(ushort u){ union{uint u; float f;} x; x.u = ((uint)u)<<16; return x.f; }
__device__ __forceinline__ ushort bdn(float f){ union{ bf16 h; ushort s;} v; v.h = __float2bfloat16(f); return v.s; }
__device__ __forceinline__ uint aff2(uint u, float a0, float b0, float a1, float b1){
  float x0 = bup((ushort)(u & 0xffff)), x1 = bup((ushort)(u >> 16));
  float y0 = fmaf(a0, x0, b0); y0 = y0 >= 0.f ? y0 : 0.01f*y0;
  float y1 = fmaf(a1, x1, b1); y1 = y1 >= 0.f ? y1 : 0.01f*y1;
  return (uint)bdn(y0) | ((uint)bdn(y1) << 16);
}
__device__ __forceinline__ f32x4 mf(frag a, frag b, f32x4 c){
  return __builtin_amdgcn_mfma_f32_16x16x32_bf16(a, b, c, 0, 0, 0);
}
__device__ __forceinline__ void acc2(uint u, float w, float& a, float& b){
  union { uint u; float f; } lo, hi;
  lo.u = u << 16; hi.u = u & 0xffff0000u;
  a = fmaf(w, lo.f, a); b = fmaf(w, hi.f, b);
}

// ---------------------------------------------------------------------------
// K0: transpose feat -> channel-last bf16, restricted to the per-batch sample
// AABB (computed from camera: pts multilinear in (u,v,d) -> vertex extremes).
// Block 0 additionally packs MFMA weight fragments + resets counters.
// ---------------------------------------------------------------------------
__global__ __launch_bounds__(256) void k_transpose(const float* __restrict__ feat,
    const float* __restrict__ R, const float* __restrict__ T, const float* __restrict__ Kin,
    const float* __restrict__ wt, const float* __restrict__ w1, const float* __restrict__ w2)
{
  __shared__ float lt[4*64*17];
  int blk = blockIdx.x;                 // b*1024 + z*16 + yq
  int yq = blk & 15, z = (blk>>4)&63, b = blk>>10;
  int y0 = yq*4;
  int tid = threadIdx.x;

  if (blk == 0){
    if (tid == 0){ g_ctr1 = 0; g_ctr2 = 0; }
    for (int idx = tid; idx < 4*5*64*8; idx += 256){
      int cls = idx / 2560; int rem = idx % 2560;
      int step = rem / 512; int rem2 = rem % 512;
      int lane = rem2 >> 3, j = rem2 & 7;
      int o = lane & 15;
      int k = step*32 + (lane>>4)*8 + j;
      int tau = k >> 4, ic = k & 15;
      int dr = cls >> 1, dc = cls & 1;
      float val = 0.f;
      if (tau < 9){
        int s = tau/3, t = tau%3;
        val = wt[(ic*16 + o)*36 + (4-2*s+dr)*6 + (4-2*t+dc)];
      }
      g_wAt[idx] = __float2bfloat16(val);
    }
    for (int idx = tid; idx < 13*64*8; idx += 256){
      int step = idx / 512; int rem2 = idx % 512;
      int lane = rem2 >> 3, j = rem2 & 7;
      int o = lane & 15;
      int k = step*32 + (lane>>4)*8 + j;
      int tau = k >> 4, ic = k & 15;
      float val = (tau < 25 && o < 8) ? w1[o*400 + ic*25 + tau] : 0.f;
      g_wA1[idx] = __float2bfloat16(val);
    }
    for (int idx = tid; idx < 7*64*8; idx += 256){
      int step = idx / 512; int rem2 = idx % 512;
      int lane = rem2 >> 3, j = rem2 & 7;
      int o = lane & 15;
      int k = step*32 + (lane>>4)*8 + j;
      int tau = k >> 3, ic = k & 7;
      float val = (tau < 25 && o < 3) ? w2[o*200 + ic*25 + tau] : 0.f;
      g_wA2[idx] = __float2bfloat16(val);
    }
  }

  // per-batch sample AABB from the 8 (u,v,d) box vertices
  float fx = Kin[b*9+0]*0.5f, fy = Kin[b*9+4]*0.5f;
  float cx = Kin[b*9+2]*0.5f, cy = Kin[b*9+5]*0.5f;
  float Rm[9];
  #pragma unroll
  for (int i=0;i<9;i++) Rm[i] = R[b*9+i];
  float T0 = T[b*3+0], T1 = T[b*3+1], T2 = T[b*3+2];
  float ox = -(Rm[0]*T0 + Rm[3]*T1 + Rm[6]*T2);
  float oy = -(Rm[1]*T0 + Rm[4]*T1 + Rm[7]*T2);
  float oz = -(Rm[2]*T0 + Rm[5]*T1 + Rm[8]*T2);
  const float SC = 2.0f*64.0f/63.0f;
  float xmn=1e30f,xmx=-1e30f,ymn=1e30f,ymx=-1e30f,zmn=1e30f,zmx=-1e30f;
  #pragma unroll
  for (int vtx=0; vtx<8; ++vtx){
    float uu = (vtx&1)? 63.5f : 0.5f;
    float vv = (vtx&2)? 63.5f : 0.5f;
    float dd = (vtx&4)? 2.8f : 1.2f;
    float dcx = (uu-cx)/fx, dcy = (vv-cy)/fy;
    float dwx = Rm[0]*dcx + Rm[3]*dcy + Rm[6];
    float dwy = Rm[1]*dcx + Rm[4]*dcy + Rm[7];
    float dwz = Rm[2]*dcx + Rm[5]*dcy + Rm[8];
    float gx = ((ox + dwx*dd)*SC + 1.0f)*31.5f;
    float gy = ((oy + dwy*dd)*SC + 1.0f)*31.5f;
    float gz = ((oz + dwz*dd)*SC + 1.0f)*31.5f;
    xmn=fminf(xmn,gx); xmx=fmaxf(xmx,gx);
    ymn=fminf(ymn,gy); ymx=fmaxf(ymx,gy);
    zmn=fminf(zmn,gz); zmx=fmaxf(zmx,gz);
  }
  int xlo = max(0,(int)floorf(xmn)), xhi = min(63,(int)floorf(xmx)+1);
  int ylo = max(0,(int)floorf(ymn)), yhi = min(63,(int)floorf(ymx)+1);
  int zlo = max(0,(int)floorf(zmn)), zhi = min(63,(int)floorf(zmx)+1);

  if (y0 > yhi || y0+3 < ylo || z > zhi || z < zlo) return;

  int xq = tid & 15;
  bool okx = (xq*4 <= xhi) && (xq*4+3 >= xlo);
  #pragma unroll
  for (int it=0; it<4; ++it){
    int cy = it*16 + (tid>>4);
    int c = cy >> 2, y = cy & 3;
    if (okx){
      const float4 vv = *(const float4*)(feat + (size_t)b*4194304 + (size_t)c*262144
                                         + z*4096 + (y0+y)*64 + xq*4);
      float* dst = &lt[(y*64 + xq*4)*17 + c];
      dst[0]=vv.x; dst[17]=vv.y; dst[34]=vv.z; dst[51]=vv.w;
    }
  }
  __syncthreads();
  int y = tid >> 6, x = tid & 63;
  int xg = x >> 2;
  if ((xg*4 <= xhi) && (xg*4+3 >= xlo)){
    const float* row = &lt[(y*64+x)*17];
    uint pk[8];
    #pragma unroll
    for (int c2=0;c2<8;c2++)
      pk[c2] = (uint)bdn(row[2*c2]) | ((uint)bdn(row[2*c2+1])<<16);
    uint* dst = (uint*)(g_volT + ((size_t)b*262144 + z*4096 + (y0+y)*64 + x)*16);
    uint4 lo; lo.x=pk[0]; lo.y=pk[1]; lo.z=pk[2]; lo.w=pk[3];
    uint4 hi; hi.x=pk[4]; hi.y=pk[5]; hi.z=pk[6]; hi.w=pk[7];
    *(uint4*)dst = lo;
    *(uint4*)(dst+4) = hi;
  }
}

// ---------------------------------------------------------------------------
// K1: render. One wave per 8x8 pixel tile, sequential 64-depth march with
// transmittance early-exit + per-lane gather predication. grid 512 x 64thr.
// ---------------------------------------------------------------------------
__global__ __launch_bounds__(64) void k_render(
    const float* __restrict__ R, const float* __restrict__ T, const float* __restrict__ Kin,
    const float* __restrict__ dens)
{
  int blk  = blockIdx.x;
  int lane = threadIdx.x;
  int b  = blk & 7;                     // XCD-pinned batch
  int t  = blk >> 3;
  int py0 = (t >> 3) * 8, px0 = (t & 7) * 8;
  int h = py0 + (lane >> 3), w = px0 + (lane & 7);

  float fx = Kin[b*9+0]*0.5f, fy = Kin[b*9+4]*0.5f;
  float cx = Kin[b*9+2]*0.5f, cy = Kin[b*9+5]*0.5f;
  float u = (float)w + 0.5f, v = (float)h + 0.5f;
  float dcx = (u - cx)/fx, dcy = (v - cy)/fy;
  float Rm[9];
  #pragma unroll
  for (int i=0;i<9;i++) Rm[i] = R[b*9+i];
  float T0 = T[b*3+0], T1 = T[b*3+1], T2 = T[b*3+2];
  float dwx = Rm[0]*dcx + Rm[3]*dcy + Rm[6];
  float dwy = Rm[1]*dcx + Rm[4]*dcy + Rm[7];
  float dwz = Rm[2]*dcx + Rm[5]*dcy + Rm[8];
  float ox = -(Rm[0]*T0 + Rm[3]*T1 + Rm[6]*T2);
  float oy = -(Rm[1]*T0 + Rm[4]*T1 + Rm[7]*T2);
  float oz = -(Rm[2]*T0 + Rm[5]*T1 + Rm[8]*T2);

  const float SC = 2.0f*64.0f/63.0f;
  const float* dp = dens + (size_t)b*262144;
  const bf16* vb = g_volT + (size_t)b*262144*16;

  float vch[16];
  #pragma unroll
  for (int c=0;c<16;c++) vch[c] = 0.f;
  float Trun = 1.0f, Pop = 1.0f;

  for (int d=0; d<64; ++d){
    float depth = 1.2f + (1.6f/63.0f) * (float)d;
    float ix = (ox + dwx*depth)*SC;  ix = (ix + 1.0f)*0.5f*63.0f;
    float iy = (oy + dwy*depth)*SC;  iy = (iy + 1.0f)*0.5f*63.0f;
    float iz = (oz + dwz*depth)*SC;  iz = (iz + 1.0f)*0.5f*63.0f;
    float xf = floorf(ix), yf = floorf(iy), zf = floorf(iz);
    int x0 = (int)xf, y0 = (int)yf, z0 = (int)zf;
    float sigma = 0.f;

    bool anyv = (x0>=-1)&(x0<64)&(y0>=-1)&(y0<64)&(z0>=-1)&(z0<64);
    if (anyv){
      float fxr = ix-xf, fyr = iy-yf, fzr = iz-zf;
      int offs[8]; float cw[8];
      #pragma unroll
      for (int k=0;k<8;k++){
        int dx = k&1, dy=(k>>1)&1, dz=(k>>2)&1;
        int xc=x0+dx, yc=y0+dy, zc=z0+dz;
        bool valid = (xc>=0)&(xc<64)&(yc>=0)&(yc<64)&(zc>=0)&(zc<64);
        float wk = (dx?fxr:1.f-fxr)*(dy?fyr:1.f-fyr)*(dz?fzr:1.f-fzr);
        cw[k] = valid ? wk : 0.0f;
        int xcc = min(max(xc,0),63), ycc=min(max(yc,0),63), zcc=min(max(zc,0),63);
        offs[k] = (zcc*64 + ycc)*64 + xcc;
      }
      #pragma unroll
      for (int k=0;k<8;k++) sigma += cw[k]*dp[offs[k]];

      float wgt = sigma * Trun;
      if (wgt > 1e-7f){
        #pragma unroll
        for (int k=0;k<8;k++){
          const uint4* p = (const uint4*)(vb + (size_t)offs[k]*16);
          uint4 q0 = p[0];
          uint4 q1 = p[1];
          float wk = cw[k]*wgt;
          acc2(q0.x, wk, vch[0],  vch[1]);
          acc2(q0.y, wk, vch[2],  vch[3]);
          acc2(q0.z, wk, vch[4],  vch[5]);
          acc2(q0.w, wk, vch[6],  vch[7]);
          acc2(q1.x, wk, vch[8],  vch[9]);
          acc2(q1.y, wk, vch[10], vch[11]);
          acc2(q1.z, wk, vch[12], vch[13]);
          acc2(q1.w, wk, vch[14], vch[15]);
        }
      }
    }
    Trun *= (1.0f + 1e-10f - sigma);
    Pop  *= (1.0f - sigma);
    if (__ballot(Trun > 1e-7f) == 0ULL) break;
  }

  g_sil[b*4096 + h*64 + w] = 1.0f - Pop;
  uint pk[8];
  #pragma unroll
  for (int c2=0;c2<8;c2++)
    pk[c2] = (uint)bdn(vch[2*c2]) | ((uint)bdn(vch[2*c2+1])<<16);
  uint* dst = (uint*)(g_imgT + ((size_t)(b*4096) + h*64 + w)*16);
  uint4 lo; lo.x=pk[0]; lo.y=pk[1]; lo.z=pk[2]; lo.w=pk[3];
  uint4 hi; hi.x=pk[4]; hi.y=pk[5]; hi.z=pk[6]; hi.w=pk[7];
  *(uint4*)dst = lo;
  *(uint4*)(dst+4) = hi;
}

// ---------------------------------------------------------------------------
// K2: ConvTranspose2d via MFMA + last-block BN1 finalize.
// ---------------------------------------------------------------------------
__global__ __launch_bounds__(256) void k_convt(const float* __restrict__ bt,
                                               const float* __restrict__ g1,
                                               const float* __restrict__ be1)
{
  __shared__ __align__(16) short tile[3*66*16];
  __shared__ float ssum[4][16], ssq[4][16];
  __shared__ float rs[256], rq[256];
  __shared__ uint s_done;

  int blk = blockIdx.x;
  int r = blk & 63, b = blk >> 6;
  int tid = threadIdx.x;

  for (int idx = tid; idx < 396; idx += 256){
    int row3 = idx / 132; int rem = idx - row3*132;
    int c2 = rem >> 1, half = rem & 1;
    int gr = r - 1 + row3, gc = c2 - 1;
    uint4 val = make_uint4(0,0,0,0);
    if (gr>=0 && gr<64 && gc>=0 && gc<64)
      val = *(const uint4*)(g_imgT + ((size_t)(b*4096) + gr*64 + gc)*16 + half*8);
    *(uint4*)(tile + (row3*66 + c2)*16 + half*8) = val;
  }
  __syncthreads();

  int wv = tid >> 6, lane = tid & 63;
  int dr = wv >> 1, dc = wv & 1;
  int quad = lane >> 4, col = lane & 15;
  int ic0 = (quad & 1) * 8;

  f32x4 acc[4];
  #pragma unroll
  for (int n=0;n<4;n++) acc[n] = (f32x4){0.f,0.f,0.f,0.f};

  #pragma unroll
  for (int s5=0; s5<5; ++s5){
    frag a = *(const frag*)(g_wAt + ((wv*5 + s5)*64 + lane)*8);
    int tau = 2*s5 + (quad >> 1);
    if (tau > 8) tau = 0;
    int ss = tau/3, tt = tau%3;
    #pragma unroll
    for (int n=0;n<4;n++){
      int c2 = n*16 + col + tt;
      frag bf = *(const frag*)(tile + (ss*66 + c2)*16 + ic0);
      acc[n] = mf(a, bf, acc[n]);
    }
  }

  float4 bo = *(const float4*)(bt + quad*4);
  float bor[4] = {bo.x, bo.y, bo.z, bo.w};
  float sv[4] = {0,0,0,0}, qv[4] = {0,0,0,0};
  int orow = 2*r + dr;
  #pragma unroll
  for (int n=0;n<4;n++){
    int ocol = 2*(n*16 + col) + dc;
    bf16* dst = g_t1 + ((size_t)(b*128 + orow)*128 + ocol)*16 + quad*4;
    #pragma unroll
    for (int reg=0;reg<4;reg++){
      float vvv = acc[n][reg] + bor[reg];
      dst[reg] = __float2bfloat16(vvv);
      sv[reg] += vvv; qv[reg] += vvv*vvv;
    }
  }
  #pragma unroll
  for (int m=1; m<16; m<<=1){
    #pragma unroll
    for (int reg=0;reg<4;reg++){
      sv[reg] += __shfl_xor(sv[reg], m, 64);
      qv[reg] += __shfl_xor(qv[reg], m, 64);
    }
  }
  if ((lane & 15) == 0){
    #pragma unroll
    for (int reg=0;reg<4;reg++){
      ssum[wv][quad*4+reg] = sv[reg];
      ssq [wv][quad*4+reg] = qv[reg];
    }
  }
  __syncthreads();
  if (tid < 16){
    g_part[blk*32 + tid]      = ssum[0][tid]+ssum[1][tid]+ssum[2][tid]+ssum[3][tid];
    g_part[blk*32 + 16 + tid] = ssq[0][tid]+ssq[1][tid]+ssq[2][tid]+ssq[3][tid];
  }
  __syncthreads();
  __threadfence();
  if (tid == 0) s_done = atomicAdd(&g_ctr1, 1u);
  __syncthreads();
  if (s_done == 511){
    __threadfence();
    int c = tid>>4, seg = tid&15;
    float s=0.f, q=0.f;
    for (int k=0;k<32;k++){
      int bb = seg*32+k;
      s += g_part[bb*32 + c];
      q += g_part[bb*32 + 16 + c];
    }
    rs[tid]=s; rq[tid]=q; __syncthreads();
    for (int sft=8; sft>0; sft>>=1){
      if (seg<sft){ rs[tid]+=rs[tid+sft]; rq[tid]+=rq[tid+sft]; }
      __syncthreads();
    }
    if (seg==0){
      float m = rs[tid]*(1.0f/131072.f);
      float v2 = rq[tid]*(1.0f/131072.f) - m*m;
      float a = g1[c]*rsqrtf(v2+1e-5f);
      g_stats[32+c] = a; g_stats[48+c] = be1[c]-m*a;
    }
  }
}

// ---------------------------------------------------------------------------
// K3: conv1 5x5 (16->8) via MFMA, BN1+leaky fused + last-block BN2 finalize.
// ---------------------------------------------------------------------------
__global__ __launch_bounds__(256) void k_conv1(const float* __restrict__ b1,
                                               const float* __restrict__ g2,
                                               const float* __restrict__ be2)
{
  __shared__ __align__(16) short tile[8*132*16];
  __shared__ float ssum[4][8], ssq[4][8];
  __shared__ float rs[256], rq[256];
  __shared__ uint s_done;

  int blk = blockIdx.x;
  int rt = blk & 31, b = blk >> 5;
  int tid = threadIdx.x;

  float pa[16], pb[16];
  #pragma unroll
  for (int c=0;c<16;c++){ pa[c] = g_stats[32+c]; pb[c] = g_stats[48+c]; }

  for (int it=0; it<5; ++it){
    int idx = it*256 + tid;
    if (idx < 1056){
      int r8 = idx / 132; int c2 = idx - r8*132;
      int gr = rt*4 - 2 + r8, gc = c2 - 2;
      uint4 v0 = make_uint4(0,0,0,0), v1 = make_uint4(0,0,0,0);
      if (gr>=0 && gr<128 && gc>=0 && gc<128){
        const bf16* src = g_t1 + ((size_t)(b*128 + gr)*128 + gc)*16;
        v0 = *(const uint4*)(src);
        v1 = *(const uint4*)(src + 8);
        v0.x = aff2(v0.x, pa[0],pb[0],pa[1],pb[1]);
        v0.y = aff2(v0.y, pa[2],pb[2],pa[3],pb[3]);
        v0.z = aff2(v0.z, pa[4],pb[4],pa[5],pb[5]);
        v0.w = aff2(v0.w, pa[6],pb[6],pa[7],pb[7]);
        v1.x = aff2(v1.x, pa[8],pb[8],pa[9],pb[9]);
        v1.y = aff2(v1.y, pa[10],pb[10],pa[11],pb[11]);
        v1.z = aff2(v1.z, pa[12],pb[12],pa[13],pb[13]);
        v1.w = aff2(v1.w, pa[14],pb[14],pa[15],pb[15]);
      }
      *(uint4*)(tile + (r8*132 + c2)*16)     = v0;
      *(uint4*)(tile + (r8*132 + c2)*16 + 8) = v1;
    }
  }
  __syncthreads();

  int wv = tid >> 6, lane = tid & 63;
  int quad = lane >> 4, col = lane & 15;
  int ic0 = (quad & 1) * 8;

  f32x4 acc[8];
  #pragma unroll
  for (int n=0;n<8;n++) acc[n] = (f32x4){0.f,0.f,0.f,0.f};

  for (int s13=0; s13<13; ++s13){
    frag a = *(const frag*)(g_wA1 + (s13*64 + lane)*8);
    int tau = 2*s13 + (quad >> 1);
    if (tau > 24) tau = 0;
    int dh = tau/5, dw = tau%5;
    int rowt = wv + dh;
    #pragma unroll
    for (int n=0;n<8;n++){
      int c2 = n*16 + col + dw;
      frag bf = *(const frag*)(tile + (rowt*132 + c2)*16 + ic0);
      acc[n] = mf(a, bf, acc[n]);
    }
  }

  int row = rt*4 + wv;
  float sv[4] = {0,0,0,0}, qv[4] = {0,0,0,0};
  if (quad < 2){
    float4 bo = *(const float4*)(b1 + quad*4);
    float bor[4] = {bo.x, bo.y, bo.z, bo.w};
    #pragma unroll
    for (int n=0;n<8;n++){
      int px = n*16 + col;
      bf16* dst = g_a2r + ((size_t)(b*128 + row)*128 + px)*8 + quad*4;
      #pragma unroll
      for (int reg=0;reg<4;reg++){
        float vvv = acc[n][reg] + bor[reg];
        dst[reg] = __float2bfloat16(vvv);
        sv[reg] += vvv; qv[reg] += vvv*vvv;
      }
    }
  }
  #pragma unroll
  for (int m=1; m<16; m<<=1){
    #pragma unroll
    for (int reg=0;reg<4;reg++){
      sv[reg] += __shfl_xor(sv[reg], m, 64);
      qv[reg] += __shfl_xor(qv[reg], m, 64);
    }
  }
  if ((lane & 15) == 0 && quad < 2){
    #pragma unroll
    for (int reg=0;reg<4;reg++){
      ssum[wv][quad*4+reg] = sv[reg];
      ssq [wv][quad*4+reg] = qv[reg];
    }
  }
  __syncthreads();
  if (tid < 8){
    g_part2[blk*16 + tid]     = ssum[0][tid]+ssum[1][tid]+ssum[2][tid]+ssum[3][tid];
    g_part2[blk*16 + 8 + tid] = ssq[0][tid]+ssq[1][tid]+ssq[2][tid]+ssq[3][tid];
  }
  __syncthreads();
  __threadfence();
  if (tid == 0) s_done = atomicAdd(&g_ctr2, 1u);
  __syncthreads();
  if (s_done == 255){
    __threadfence();
    int seg = tid & 31, c = tid >> 5;
    float s=0.f, q=0.f;
    for (int k=0;k<8;k++){
      int bb = seg*8+k;
      s += g_part2[bb*16 + c];
      q += g_part2[bb*16 + 8 + c];
    }
    rs[tid]=s; rq[tid]=q; __syncthreads();
    for (int sft=16; sft>0; sft>>=1){
      if (seg<sft){ rs[tid]+=rs[tid+sft]; rq[tid]+=rq[tid+sft]; }
      __syncthreads();
    }
    if (seg==0){
      float m = rs[tid]*(1.0f/131072.f);
      float v2 = rq[tid]*(1.0f/131072.f) - m*m;
      float a = g2[c]*rsqrtf(v2+1e-5f);
      g_stats[80+c] = a; g_stats[88+c] = be2[c]-m*a;
    }
  }
}

// ---------------------------------------------------------------------------
// K4: conv2 5x5 (8->3) via MFMA (blocks 0..255) + silhouette upsample
// (blocks 256..767). BN2+leaky fused; ReLU -> d_out.
// ---------------------------------------------------------------------------
__global__ __launch_bounds__(256) void k_conv2(float* __restrict__ outp,
                                               const float* __restrict__ b2)
{
  __shared__ __align__(16) short tile[8*132*8];

  int blk = blockIdx.x;
  int tid = threadIdx.x;

  if (blk >= 256){
    int idx = (blk-256)*256 + tid;
    int b = idx >> 14;
    int y = (idx >> 7) & 127;
    int x = idx & 127;
    float sy = y*0.5f - 0.25f, sx = x*0.5f - 0.25f;
    float yfl = floorf(sy), xfl = floorf(sx);
    float fy = sy - yfl, fxx = sx - xfl;
    int y0 = min(max((int)yfl,0),63), y1 = min(max((int)yfl+1,0),63);
    int x0 = min(max((int)xfl,0),63), x1 = min(max((int)xfl+1,0),63);
    const float* s = g_sil + b*4096;
    float vv = (1.f-fy)*((1.f-fxx)*s[y0*64+x0] + fxx*s[y0*64+x1])
             +      fy *((1.f-fxx)*s[y1*64+x0] + fxx*s[y1*64+x1]);
    outp[393216 + idx] = vv;
    return;
  }

  int rt = blk & 31, b = blk >> 5;

  float pa[8], pb[8];
  #pragma unroll
  for (int c=0;c<8;c++){ pa[c] = g_stats[80+c]; pb[c] = g_stats[88+c]; }

  for (int it=0; it<5; ++it){
    int idx = it*256 + tid;
    if (idx < 1056){
      int r8 = idx / 132; int c2 = idx - r8*132;
      int gr = rt*4 - 2 + r8, gc = c2 - 2;
      uint4 v0 = make_uint4(0,0,0,0);
      if (gr>=0 && gr<128 && gc>=0 && gc<128){
        v0 = *(const uint4*)(g_a2r + ((size_t)(b*128 + gr)*128 + gc)*8);
        v0.x = aff2(v0.x, pa[0],pb[0],pa[1],pb[1]);
        v0.y = aff2(v0.y, pa[2],pb[2],pa[3],pb[3]);
        v0.z = aff2(v0.z, pa[4],pb[4],pa[5],pb[5]);
        v0.w = aff2(v0.w, pa[6],pb[6],pa[7],pb[7]);
      }
      *(uint4*)(tile + (r8*132 + c2)*8) = v0;
    }
  }
  __syncthreads();

  int wv = tid >> 6, lane = tid & 63;
  int quad = lane >> 4, col = lane & 15;

  f32x4 acc[8];
  #pragma unroll
  for (int n=0;n<8;n++) acc[n] = (f32x4){0.f,0.f,0.f,0.f};

  for (int s7=0; s7<7; ++s7){
    frag a = *(const frag*)(g_wA2 + (s7*64 + lane)*8);
    int tau = 4*s7 + quad;
    if (tau > 24) tau = 0;
    int dh = tau/5, dw = tau%5;
    int rowt = wv + dh;
    #pragma unroll
    for (int n=0;n<8;n++){
      int c2 = n*16 + col + dw;
      frag bf = *(const frag*)(tile + (rowt*132 + c2)*8);
      acc[n] = mf(a, bf, acc[n]);
    }
  }

  if (quad == 0){
    int row = rt*4 + wv;
    float b2v[3] = {b2[0], b2[1], b2[2]};
    #pragma unroll
    for (int n=0;n<8;n++){
      int px = n*16 + col;
      #pragma unroll
      for (int reg=0;reg<3;reg++){
        float vvv = fmaxf(acc[n][reg] + b2v[reg], 0.f);
        outp[(size_t)(b*3 + reg)*16384 + row*128 + px] = vvv;
      }
    }
  }
}

// ---------------------------------------------------------------------------
extern "C" void kernel_launch(void* const* d_in, const int* in_sizes, int n_in,
                              void* d_out, int out_size, void* d_ws, size_t ws_size,
                              hipStream_t stream)
{
  const float* R    = (const float*)d_in[0];
  const float* T    = (const float*)d_in[1];
  const float* K    = (const float*)d_in[2];
  const float* feat = (const float*)d_in[3];
  const float* dens = (const float*)d_in[4];
  const float* wt   = (const float*)d_in[5];
  const float* bt   = (const float*)d_in[6];
  const float* g1   = (const float*)d_in[7];
  const float* be1  = (const float*)d_in[8];
  const float* w1   = (const float*)d_in[9];
  const float* b1   = (const float*)d_in[10];
  const float* g2   = (const float*)d_in[11];
  const float* be2  = (const float*)d_in[12];
  const float* w2   = (const float*)d_in[13];
  const float* b2   = (const float*)d_in[14];

  k_transpose<<<8192, 256, 0, stream>>>(feat, R, T, K, wt, w1, w2);
  k_render   <<<512, 64, 0, stream>>>(R, T, K, dens);
  k_convt    <<<512, 256, 0, stream>>>(bt, g1, be1);
  k_conv1    <<<256, 256, 0, stream>>>(b1, g2, be2);
  k_conv2    <<<768, 256, 0, stream>>>((float*)d_out, b2);
}